// Round 7
// baseline (396.867 us; speedup 1.0000x reference)
//
#include <hip/hip_runtime.h>

#define B_   2
#define LQ   1024
#define LIN  4096
#define CH   256
#define MH   8
#define NP   4
#define NROW (B_ * LQ)                  // 2048 (b,q) rows
#define NPTS (NROW * MH * NP)           // 65536 sampling points

// spatial hash grid for exact KNN: 16^3 cells over [-5.12, 5.12]
#define GN   16
#define GN3  (GN * GN * GN)             // 4096 cells
#define GH   0.64f
#define GX0  (-5.12f)
#define GINV 1.5625f                    // 1/GH
#define GEPS 1e-3f                      // pruning slack (absolute, on squared dist)

// LDS row-swizzle for the GEMM kernels (<=2-way bank aliasing on b128 frags)
#define SWZ(r) ((((r) >> 2) & 7) << 2)

// ---------------------------------------------------------------------------
// Fused S-path: S = query @ [Ws;Wa]^T + [bs;ba] (2048 x 128), then directly
//   loc[b,q,m,p,:] = query_points + S[row][m*12+p*3+e]
//   attw[b,q,m,p]  = softmax_p(S[row][96+m*4+p])
// 32 rows x 128 cols per block -> 64 blocks. 256 threads, 2x8 micro, BK=16.
// ---------------------------------------------------------------------------
__global__ __launch_bounds__(256)
void gemm_s_fused(const float* __restrict__ query,
                  const float* __restrict__ Ws, const float* __restrict__ bs,
                  const float* __restrict__ Wa, const float* __restrict__ ba,
                  const float* __restrict__ qpts,
                  float* __restrict__ loc, float* __restrict__ attw) {
    __shared__ float As[16][32];
    __shared__ float Bs[16][128];
    __shared__ float Ss[32][132];
    const int tid = threadIdx.x;
    const int rowbase = blockIdx.x * 32;
    const int tx = tid & 15;          // col group (8 cols)
    const int ty = tid >> 4;          // row group (2 rows)

    const int lr  = tid >> 3;         // A-staging row 0..31
    const int lka = (tid & 7) * 2;    // A-staging k (float2)
    const float* Ap = query + (size_t)(rowbase + lr) * CH + lka;
    const int n   = tid >> 1;         // B-staging weight row
    const int lkb = (tid & 1) * 8;
    const float* Wrow = ((n < 96) ? (Ws + (size_t)n * CH)
                                  : (Wa + (size_t)(n - 96) * CH)) + lkb;
    float bj[8];
#pragma unroll
    for (int j = 0; j < 8; ++j) {
        int col = tx * 8 + j;
        bj[j] = (col < 96) ? bs[col] : ba[col - 96];
    }

    float2 a0 = *reinterpret_cast<const float2*>(Ap);
    float4 b0 = *reinterpret_cast<const float4*>(Wrow);
    float4 b1 = *reinterpret_cast<const float4*>(Wrow + 4);

    float acc[2][8] = {};
    for (int k0 = 0; k0 < CH; k0 += 16) {
        __syncthreads();
        As[lka + 0][lr] = a0.x; As[lka + 1][lr] = a0.y;
        Bs[lkb + 0][n] = b0.x; Bs[lkb + 1][n] = b0.y;
        Bs[lkb + 2][n] = b0.z; Bs[lkb + 3][n] = b0.w;
        Bs[lkb + 4][n] = b1.x; Bs[lkb + 5][n] = b1.y;
        Bs[lkb + 6][n] = b1.z; Bs[lkb + 7][n] = b1.w;
        __syncthreads();
        if (k0 + 16 < CH) {
            a0 = *reinterpret_cast<const float2*>(Ap + k0 + 16);
            b0 = *reinterpret_cast<const float4*>(Wrow + k0 + 16);
            b1 = *reinterpret_cast<const float4*>(Wrow + k0 + 20);
        }
#pragma unroll
        for (int k = 0; k < 16; ++k) {
            float2 a  = *reinterpret_cast<const float2*>(&As[k][ty << 1]);
            float4 v0 = *reinterpret_cast<const float4*>(&Bs[k][tx * 8]);
            float4 v1 = *reinterpret_cast<const float4*>(&Bs[k][tx * 8 + 4]);
            float ar[2] = {a.x, a.y};
            float br[8] = {v0.x, v0.y, v0.z, v0.w, v1.x, v1.y, v1.z, v1.w};
#pragma unroll
            for (int i = 0; i < 2; ++i)
#pragma unroll
                for (int j = 0; j < 8; ++j)
                    acc[i][j] = fmaf(ar[i], br[j], acc[i][j]);
        }
    }

    __syncthreads();
#pragma unroll
    for (int i = 0; i < 2; ++i)
#pragma unroll
        for (int j = 0; j < 8; ++j)
            Ss[ty * 2 + i][tx * 8 + j] = acc[i][j] + bj[j];
    __syncthreads();

    {   // epilogue: 256 units = 32 rows x 8 heads
        int row = tid >> 3;
        int m   = tid & 7;
        int r   = rowbase + row;
        const float* Sr = Ss[row];
        float q0 = qpts[r * 3 + 0], q1 = qpts[r * 3 + 1], q2 = qpts[r * 3 + 2];
#pragma unroll
        for (int p = 0; p < NP; ++p) {
            size_t o = ((size_t)(r * MH + m) * NP + p) * 3;
            loc[o + 0] = q0 + Sr[m * 12 + p * 3 + 0];
            loc[o + 1] = q1 + Sr[m * 12 + p * 3 + 1];
            loc[o + 2] = q2 + Sr[m * 12 + p * 3 + 2];
        }
        float l0 = Sr[96 + m * 4 + 0], l1 = Sr[96 + m * 4 + 1];
        float l2 = Sr[96 + m * 4 + 2], l3 = Sr[96 + m * 4 + 3];
        float mx = fmaxf(fmaxf(l0, l1), fmaxf(l2, l3));
        float e0 = expf(l0 - mx), e1 = expf(l1 - mx);
        float e2 = expf(l2 - mx), e3 = expf(l3 - mx);
        float inv = 1.0f / (e0 + e1 + e2 + e3);
        size_t ao = (size_t)(r * MH + m) * NP;
        attw[ao + 0] = e0 * inv; attw[ao + 1] = e1 * inv;
        attw[ao + 2] = e2 * inv; attw[ao + 3] = e3 * inv;
    }
}

// ---------------------------------------------------------------------------
// Counting-sort the candidate points into a 16^3 grid (per batch).
// spts[b][pos] = (x, y, z, bits(orig_idx)) sorted by cell;
// cellstart[b][c..c+1) = cell range. One block per batch, 512 threads.
// ---------------------------------------------------------------------------
__global__ __launch_bounds__(512)
void build_grid_kernel(const float* __restrict__ ipts,
                       float4* __restrict__ spts, int* __restrict__ cellstart) {
    __shared__ int hist[GN3];
    __shared__ int part[512];
    const int b = blockIdx.x;
    const int t = threadIdx.x;
    const float* pb = ipts + (size_t)b * LIN * 3;

#pragma unroll
    for (int k = 0; k < GN3 / 512; ++k) hist[k * 512 + t] = 0;
    __syncthreads();

    int cells[LIN / 512];
#pragma unroll
    for (int k = 0; k < LIN / 512; ++k) {
        int i = k * 512 + t;
        float x = pb[i * 3 + 0], y = pb[i * 3 + 1], z = pb[i * 3 + 2];
        int cx = min(max((int)floorf((x - GX0) * GINV), 0), GN - 1);
        int cy = min(max((int)floorf((y - GX0) * GINV), 0), GN - 1);
        int cz = min(max((int)floorf((z - GX0) * GINV), 0), GN - 1);
        cells[k] = (cz * GN + cy) * GN + cx;
        atomicAdd(&hist[cells[k]], 1);
    }
    __syncthreads();

    // exclusive scan over 4096: per-thread serial(8) + Hillis-Steele(512)
    int h8[8];
    int sum = 0;
#pragma unroll
    for (int k = 0; k < 8; ++k) { h8[k] = hist[t * 8 + k]; sum += h8[k]; }
    part[t] = sum;
    __syncthreads();
    for (int off = 1; off < 512; off <<= 1) {
        int v = (t >= off) ? part[t - off] : 0;
        __syncthreads();
        part[t] += v;
        __syncthreads();
    }
    int base = part[t] - sum;
    const int cb = b * (GN3 + 1);
#pragma unroll
    for (int k = 0; k < 8; ++k) {
        int c = t * 8 + k;
        cellstart[cb + c] = base;
        hist[c] = base;                  // becomes the scatter cursor
        base += h8[k];
    }
    if (t == 511) cellstart[cb + GN3] = LIN;
    __syncthreads();

#pragma unroll
    for (int k = 0; k < LIN / 512; ++k) {
        int i = k * 512 + t;
        float x = pb[i * 3 + 0], y = pb[i * 3 + 1], z = pb[i * 3 + 2];
        int pos = atomicAdd(&hist[cells[k]], 1);
        spts[(size_t)b * LIN + pos] = make_float4(x, y, z, __int_as_float(i));
    }
}

// ---------------------------------------------------------------------------
// Wave-cooperative exact grid KNN. One wave per (b,q) row: the row's 32
// sampling points form one spatial cluster (query_point + ~N(0,0.32) offsets).
// Lane l owns point (l & 31); the two 32-lane halves split each cell's
// candidates by parity and merge at the end (shfl_xor 32, lex rule).
// The WHOLE wave walks one shell sequence around lane-0's cell:
//   - loops are wave-uniform (zero control divergence)
//   - cell skip only if ALL lanes prune it (per-lane exact box LB, __all)
//   - ring stop: ring r is >= (r-dl-1)*GH from a lane whose cell is dl
//     (Chebyshev) from the center -> lane_done is exact & monotone; break
//     on __all(lane_done); every unvisited cell is then prunable per lane.
//   - candidate loads are all-lanes-same-address (broadcast, L2-resident)
// Candidate metric/tie rule identical to the rounds that passed:
//   d = |v|^2 - 2 s.v (fmaf chain), lex (d, orig_idx) -> order-independent.
// Round-6 failure mode this fixes: 1 wave/SIMD + divergent pointer-chasing
// (VALUBusy 11%, occ 5.7%) -> 2048 coherent waves, dense VALU.
// ---------------------------------------------------------------------------
__global__ __launch_bounds__(256)
void knn_row_kernel(const float* __restrict__ loc, const float4* __restrict__ spts,
                    const int* __restrict__ cellstart, int* __restrict__ idx) {
    const int wid  = (blockIdx.x * 256 + threadIdx.x) >> 6;   // row id [0, NROW)
    const int lane = threadIdx.x & 63;
    const int l32  = lane & 31;
    const int half = lane >> 5;
    const int b    = wid >> 10;
    const int gq   = wid * 32 + l32;                          // sampling point

    const float sx = loc[(size_t)gq * 3 + 0];
    const float sy = loc[(size_t)gq * 3 + 1];
    const float sz = loc[(size_t)gq * 3 + 2];
    const float sx2 = -2.f * sx, sy2 = -2.f * sy, sz2 = -2.f * sz;
    const float ssq = fmaf(sz, sz, fmaf(sy, sy, sx * sx));

    const int icx = min(max((int)floorf((sx - GX0) * GINV), 0), GN - 1);
    const int icy = min(max((int)floorf((sy - GX0) * GINV), 0), GN - 1);
    const int icz = min(max((int)floorf((sz - GX0) * GINV), 0), GN - 1);

    // wave-uniform center cell (lane 0's); dl = Chebyshev(lane cell, center)
    const int ccx = __builtin_amdgcn_readfirstlane(icx);
    const int ccy = __builtin_amdgcn_readfirstlane(icy);
    const int ccz = __builtin_amdgcn_readfirstlane(icz);
    const int dl  = max(max(abs(icx - ccx), abs(icy - ccy)), abs(icz - ccz));

    const int cb = b * (GN3 + 1);
    const float4* sb = spts + (size_t)b * LIN;

    float bd = 1e30f;
    int   bi = 0;

    for (int r = 0; r < 2 * GN; ++r) {
        int   g    = r - dl - 1;
        float rb   = (float)g * GH;
        bool  done = (g >= 0) && (rb * rb > bd + ssq + GEPS);
        if (__all(done)) break;

        int zlo = max(ccz - r, 0), zhi = min(ccz + r, GN - 1);
        int ylo = max(ccy - r, 0), yhi = min(ccy + r, GN - 1);
        int xlo = max(ccx - r, 0), xhi = min(ccx + r, GN - 1);
        for (int cz = zlo; cz <= zhi; ++cz) {
            int az = abs(cz - ccz);
            for (int cy = ylo; cy <= yhi; ++cy) {
                int ay = max(az, abs(cy - ccy));
                for (int cx = xlo; cx <= xhi; ++cx) {
                    if (max(ay, abs(cx - ccx)) != r) continue;   // shell only
                    // per-lane exact box LB (squared, true distance)
                    float lox = GX0 + cx * GH;
                    float loy = GX0 + cy * GH;
                    float loz = GX0 + cz * GH;
                    float dx = fmaxf(fmaxf(lox - sx, sx - (lox + GH)), 0.f);
                    float dy = fmaxf(fmaxf(loy - sy, sy - (loy + GH)), 0.f);
                    float dz = fmaxf(fmaxf(loz - sz, sz - (loz + GH)), 0.f);
                    float lbsq = fmaf(dx, dx, fmaf(dy, dy, dz * dz));
                    if (__all(lbsq > bd + ssq + GEPS)) continue;
                    int c  = (cz * GN + cy) * GN + cx;
                    int s0 = cellstart[cb + c];
                    int s1 = cellstart[cb + c + 1];
                    for (int j = s0 + half; j < s1; j += 2) {
                        float4 sp = sb[j];
                        float nrm = fmaf(sp.z, sp.z, fmaf(sp.y, sp.y, sp.x * sp.x));
                        float d   = fmaf(sx2, sp.x, fmaf(sy2, sp.y, fmaf(sz2, sp.z, nrm)));
                        int   oi  = __float_as_int(sp.w);
                        bool take = (d < bd) || (d == bd && oi < bi);
                        bi = take ? oi : bi;
                        bd = fminf(bd, d);
                    }
                }
            }
        }
    }

    // merge the two parity halves (lex first-min)
    float obd = __shfl_xor(bd, 32);
    int   obi = __shfl_xor(bi, 32);
    bool tk = (obd < bd) || (obd == bd && obi < bi);
    bi = tk ? obi : bi;
    if (half == 0) idx[gq] = bi;
}

// ---------------------------------------------------------------------------
// blend_gemm: out1_m = (sum_p attw_p * inp[idx_p]) @ Wv_m^T   (per head m)
// sum_p attw = 1 linearity: 16.8M-MAC blend + 134M-MAC thin GEMM replaces
// the 537M-MAC value GEMM + gather. part[ks][((m*NROW+bq)*32+d)]
// ---------------------------------------------------------------------------
__global__ __launch_bounds__(256)
void blend_gemm_kernel(const float* __restrict__ inp, const float* __restrict__ attw,
                       const int* __restrict__ idx,
                       const float* __restrict__ Wv, float* __restrict__ part) {
    __shared__ float Ab[128][132];   // blended rows, k-major, swizzled
    __shared__ float Bs[32][132];    // Wv_m half, k-major, swizzled
    __shared__ int   ids[128][4];
    __shared__ float ats[128][4];
    const int t  = threadIdx.x;
    const int rb = blockIdx.x * 128;     // bq base
    const int m  = blockIdx.y;
    const int ks = blockIdx.z;
    const int k0 = ks * 128;

    if (t < 128) {
        size_t base = ((size_t)(rb + t) * MH + m) * NP;
#pragma unroll
        for (int p = 0; p < NP; ++p) {
            ids[t][p] = idx[base + p];
            ats[t][p] = attw[base + p];
        }
    }
#pragma unroll
    for (int pass = 0; pass < 4; ++pass) {
        int u  = pass * 256 + t;
        int nn = u >> 5;                 // 0..31
        int cg = (u & 31) * 4;           // 0..124
        float4 w = *reinterpret_cast<const float4*>(Wv + (size_t)(m * 32 + nn) * CH + k0 + cg);
        *reinterpret_cast<float4*>(&Bs[nn][cg ^ SWZ(nn)]) = w;
    }
    __syncthreads();

#pragma unroll
    for (int pass = 0; pass < 16; ++pass) {
        int u   = pass * 256 + t;
        int row = u >> 5;                // 0..127
        int cg  = (u & 31) * 4;          // coalesced 512B per row-group
        int bq  = rb + row;
        const float* ib = inp + ((size_t)(bq >> 10) * LIN) * CH + k0 + cg;
        float4 a = {0.f, 0.f, 0.f, 0.f};
#pragma unroll
        for (int p = 0; p < NP; ++p) {
            float4 v = *reinterpret_cast<const float4*>(ib + (size_t)ids[row][p] * CH);
            float w = ats[row][p];
            a.x = fmaf(w, v.x, a.x); a.y = fmaf(w, v.y, a.y);
            a.z = fmaf(w, v.z, a.z); a.w = fmaf(w, v.w, a.w);
        }
        *reinterpret_cast<float4*>(&Ab[row][cg ^ SWZ(row)]) = a;
    }
    __syncthreads();

    const int ty = t >> 3;               // 0..31 -> rows ty*4..
    const int tx = t & 7;                // 0..7  -> cols tx*4..
    const int sA = SWZ(ty * 4);
    const int sB = SWZ(tx * 4);
    float acc[4][4] = {};
    for (int k = 0; k < 128; k += 4) {
        float4 a[4], bb[4];
#pragma unroll
        for (int i = 0; i < 4; ++i)
            a[i] = *reinterpret_cast<const float4*>(&Ab[ty * 4 + i][k ^ sA]);
#pragma unroll
        for (int j = 0; j < 4; ++j)
            bb[j] = *reinterpret_cast<const float4*>(&Bs[tx * 4 + j][k ^ sB]);
#pragma unroll
        for (int i = 0; i < 4; ++i)
#pragma unroll
            for (int j = 0; j < 4; ++j)
                acc[i][j] = fmaf(a[i].x, bb[j].x, fmaf(a[i].y, bb[j].y,
                             fmaf(a[i].z, bb[j].z, fmaf(a[i].w, bb[j].w, acc[i][j]))));
    }
#pragma unroll
    for (int i = 0; i < 4; ++i) {
        int bq = rb + ty * 4 + i;
        float4 c = {acc[i][0], acc[i][1], acc[i][2], acc[i][3]};
        *reinterpret_cast<float4*>(part + ((size_t)ks * MH * NROW + (size_t)m * NROW + bq) * 32 + tx * 4) = c;
    }
}

// ---------------------------------------------------------------------------
// out_gemm: out = (part0 + part1 + bv) @ Wo^T + bo   (2048 x 256, K=256)
// 64x32 tiles -> grid (32,8) = 256 blocks.
// ---------------------------------------------------------------------------
__global__ __launch_bounds__(256)
void out_gemm_kernel(const float* __restrict__ part, const float* __restrict__ bv,
                     const float* __restrict__ Wo, const float* __restrict__ bo,
                     float* __restrict__ out) {
    __shared__ float Ab[64][260];
    __shared__ float Bs[32][260];
    const int t  = threadIdx.x;
    const int rb = blockIdx.x * 64;
    const int nb = blockIdx.y * 32;

#pragma unroll
    for (int pass = 0; pass < 16; ++pass) {
        int u   = pass * 256 + t;
        int row = u >> 6;                // 0..63
        int cg  = (u & 63) * 4;          // 0..252
        int bq  = rb + row;
        int mm  = cg >> 5, d = cg & 31;
        size_t pi = ((size_t)mm * NROW + bq) * 32 + d;
        float4 v0 = *reinterpret_cast<const float4*>(part + pi);
        float4 v1 = *reinterpret_cast<const float4*>(part + (size_t)MH * NROW * 32 + pi);
        float4 bb = *reinterpret_cast<const float4*>(bv + cg);
        float4 a  = {v0.x + v1.x + bb.x, v0.y + v1.y + bb.y,
                     v0.z + v1.z + bb.z, v0.w + v1.w + bb.w};
        *reinterpret_cast<float4*>(&Ab[row][cg ^ SWZ(row)]) = a;
    }
#pragma unroll
    for (int pass = 0; pass < 8; ++pass) {
        int u  = pass * 256 + t;
        int nn = u >> 6;                 // 0..31
        int cg = (u & 63) * 4;
        float4 w = *reinterpret_cast<const float4*>(Wo + (size_t)(nb + nn) * CH + cg);
        *reinterpret_cast<float4*>(&Bs[nn][cg ^ SWZ(nn)]) = w;
    }
    __syncthreads();

    const int ty = t >> 3;               // 0..31 -> rows ty*2..
    const int tx = t & 7;                // 0..7  -> cols tx*4..
    const int sA = SWZ(ty * 2);
    const int sB = SWZ(tx * 4);
    float acc[2][4] = {};
    for (int k = 0; k < 256; k += 4) {
        float4 a[2], bb[4];
#pragma unroll
        for (int i = 0; i < 2; ++i)
            a[i] = *reinterpret_cast<const float4*>(&Ab[ty * 2 + i][k ^ sA]);
#pragma unroll
        for (int j = 0; j < 4; ++j)
            bb[j] = *reinterpret_cast<const float4*>(&Bs[tx * 4 + j][k ^ sB]);
#pragma unroll
        for (int i = 0; i < 2; ++i)
#pragma unroll
            for (int j = 0; j < 4; ++j)
                acc[i][j] = fmaf(a[i].x, bb[j].x, fmaf(a[i].y, bb[j].y,
                             fmaf(a[i].z, bb[j].z, fmaf(a[i].w, bb[j].w, acc[i][j]))));
    }
#pragma unroll
    for (int i = 0; i < 2; ++i) {
        int bq = rb + ty * 2 + i;
        int n  = nb + tx * 4;
        float4 c = {acc[i][0] + bo[n + 0], acc[i][1] + bo[n + 1],
                    acc[i][2] + bo[n + 2], acc[i][3] + bo[n + 3]};
        *reinterpret_cast<float4*>(out + (size_t)bq * CH + n) = c;
    }
}

// ---------------------------------------------------------------------------
extern "C" void kernel_launch(void* const* d_in, const int* in_sizes, int n_in,
                              void* d_out, int out_size, void* d_ws, size_t ws_size,
                              hipStream_t stream) {
    const float* query = (const float*)d_in[0];
    const float* qpts  = (const float*)d_in[1];
    const float* inp   = (const float*)d_in[2];
    const float* ipts  = (const float*)d_in[3];
    const float* Wv    = (const float*)d_in[4];
    const float* bv    = (const float*)d_in[5];
    const float* Ws    = (const float*)d_in[6];
    const float* bs    = (const float*)d_in[7];
    const float* Wa    = (const float*)d_in[8];
    const float* ba    = (const float*)d_in[9];
    const float* Wo    = (const float*)d_in[10];
    const float* bo    = (const float*)d_in[11];
    float* out = (float*)d_out;

    // workspace layout (~5.8 MB); every buffer fully overwritten each call
    float*  ws        = (float*)d_ws;
    float*  loc       = ws;                                  // NPTS*3 f
    float*  attw      = loc + (size_t)NPTS * 3;              // NPTS f
    float*  part      = attw + (size_t)NPTS;                 // 2*MH*NROW*32 f
    float4* spts      = (float4*)(part + (size_t)2 * MH * NROW * 32); // B*LIN f4
    int*    idx       = (int*)(spts + (size_t)B_ * LIN);     // NPTS i
    int*    cellstart = idx + (size_t)NPTS;                  // B*(GN3+1) i

    // 1. counting-sort candidates into the 16^3 grid (independent of 2.)
    build_grid_kernel<<<B_, 512, 0, stream>>>(ipts, spts, cellstart);
    // 2. S-path GEMM -> sampling locations + softmax weights
    gemm_s_fused<<<NROW / 32, 256, 0, stream>>>(query, Ws, bs, Wa, ba, qpts,
                                                loc, attw);
    // 3. wave-cooperative exact grid KNN (one wave per (b,q) row)
    knn_row_kernel<<<NROW / 4, 256, 0, stream>>>(loc, spts, cellstart, idx);
    // 4. gather-blend + per-head value GEMM (134M MAC)
    blend_gemm_kernel<<<dim3(NROW / 128, MH, 2), 256, 0, stream>>>(
        inp, attw, idx, Wv, part);
    // 5. output GEMM, merging K-halves + value bias (134M MAC)
    out_gemm_kernel<<<dim3(NROW / 64, CH / 32), 256, 0, stream>>>(
        part, bv, Wo, bo, out);
}

// Round 8
// 320.480 us; speedup vs baseline: 1.2384x; 1.2384x over previous
//
#include <hip/hip_runtime.h>

#define B_   2
#define LQ   1024
#define LIN  4096
#define CH   256
#define MH   8
#define NP   4
#define NROW (B_ * LQ)                  // 2048 (b,q) rows
#define NPTS (NROW * MH * NP)           // 65536 sampling points

// spatial sort grid (16^3) — used only to ORDER candidates; knn never walks it
#define GN   16
#define GN3  (GN * GN * GN)
#define GH   0.64f
#define GX0  (-5.12f)
#define GINV 1.5625f
#define GEPS 1e-3f                      // pruning slack (absolute, squared dist)

#define NGRP 512                        // groups of 8 sorted candidates
#define GSZ  8

// LDS row-swizzle for the GEMM kernels (<=2-way bank aliasing on b128 frags)
#define SWZ(r) ((((r) >> 2) & 7) << 2)

// ---------------------------------------------------------------------------
// Fused S-path: S = query @ [Ws;Wa]^T + [bs;ba] (2048 x 128), then directly
//   loc[b,q,m,p,:] = query_points + S[row][m*12+p*3+e]
//   attw[b,q,m,p]  = softmax_p(S[row][96+m*4+p])
// 32 rows x 128 cols per block -> 64 blocks. 256 threads, 2x8 micro, BK=16.
// ---------------------------------------------------------------------------
__global__ __launch_bounds__(256)
void gemm_s_fused(const float* __restrict__ query,
                  const float* __restrict__ Ws, const float* __restrict__ bs,
                  const float* __restrict__ Wa, const float* __restrict__ ba,
                  const float* __restrict__ qpts,
                  float* __restrict__ loc, float* __restrict__ attw) {
    __shared__ float As[16][32];
    __shared__ float Bs[16][128];
    __shared__ float Ss[32][132];
    const int tid = threadIdx.x;
    const int rowbase = blockIdx.x * 32;
    const int tx = tid & 15;          // col group (8 cols)
    const int ty = tid >> 4;          // row group (2 rows)

    const int lr  = tid >> 3;         // A-staging row 0..31
    const int lka = (tid & 7) * 2;    // A-staging k (float2)
    const float* Ap = query + (size_t)(rowbase + lr) * CH + lka;
    const int n   = tid >> 1;         // B-staging weight row
    const int lkb = (tid & 1) * 8;
    const float* Wrow = ((n < 96) ? (Ws + (size_t)n * CH)
                                  : (Wa + (size_t)(n - 96) * CH)) + lkb;
    float bj[8];
#pragma unroll
    for (int j = 0; j < 8; ++j) {
        int col = tx * 8 + j;
        bj[j] = (col < 96) ? bs[col] : ba[col - 96];
    }

    float2 a0 = *reinterpret_cast<const float2*>(Ap);
    float4 b0 = *reinterpret_cast<const float4*>(Wrow);
    float4 b1 = *reinterpret_cast<const float4*>(Wrow + 4);

    float acc[2][8] = {};
    for (int k0 = 0; k0 < CH; k0 += 16) {
        __syncthreads();
        As[lka + 0][lr] = a0.x; As[lka + 1][lr] = a0.y;
        Bs[lkb + 0][n] = b0.x; Bs[lkb + 1][n] = b0.y;
        Bs[lkb + 2][n] = b0.z; Bs[lkb + 3][n] = b0.w;
        Bs[lkb + 4][n] = b1.x; Bs[lkb + 5][n] = b1.y;
        Bs[lkb + 6][n] = b1.z; Bs[lkb + 7][n] = b1.w;
        __syncthreads();
        if (k0 + 16 < CH) {
            a0 = *reinterpret_cast<const float2*>(Ap + k0 + 16);
            b0 = *reinterpret_cast<const float4*>(Wrow + k0 + 16);
            b1 = *reinterpret_cast<const float4*>(Wrow + k0 + 20);
        }
#pragma unroll
        for (int k = 0; k < 16; ++k) {
            float2 a  = *reinterpret_cast<const float2*>(&As[k][ty << 1]);
            float4 v0 = *reinterpret_cast<const float4*>(&Bs[k][tx * 8]);
            float4 v1 = *reinterpret_cast<const float4*>(&Bs[k][tx * 8 + 4]);
            float ar[2] = {a.x, a.y};
            float br[8] = {v0.x, v0.y, v0.z, v0.w, v1.x, v1.y, v1.z, v1.w};
#pragma unroll
            for (int i = 0; i < 2; ++i)
#pragma unroll
                for (int j = 0; j < 8; ++j)
                    acc[i][j] = fmaf(ar[i], br[j], acc[i][j]);
        }
    }

    __syncthreads();
#pragma unroll
    for (int i = 0; i < 2; ++i)
#pragma unroll
        for (int j = 0; j < 8; ++j)
            Ss[ty * 2 + i][tx * 8 + j] = acc[i][j] + bj[j];
    __syncthreads();

    {   // epilogue: 256 units = 32 rows x 8 heads
        int row = tid >> 3;
        int m   = tid & 7;
        int r   = rowbase + row;
        const float* Sr = Ss[row];
        float q0 = qpts[r * 3 + 0], q1 = qpts[r * 3 + 1], q2 = qpts[r * 3 + 2];
#pragma unroll
        for (int p = 0; p < NP; ++p) {
            size_t o = ((size_t)(r * MH + m) * NP + p) * 3;
            loc[o + 0] = q0 + Sr[m * 12 + p * 3 + 0];
            loc[o + 1] = q1 + Sr[m * 12 + p * 3 + 1];
            loc[o + 2] = q2 + Sr[m * 12 + p * 3 + 2];
        }
        float l0 = Sr[96 + m * 4 + 0], l1 = Sr[96 + m * 4 + 1];
        float l2 = Sr[96 + m * 4 + 2], l3 = Sr[96 + m * 4 + 3];
        float mx = fmaxf(fmaxf(l0, l1), fmaxf(l2, l3));
        float e0 = expf(l0 - mx), e1 = expf(l1 - mx);
        float e2 = expf(l2 - mx), e3 = expf(l3 - mx);
        float inv = 1.0f / (e0 + e1 + e2 + e3);
        size_t ao = (size_t)(r * MH + m) * NP;
        attw[ao + 0] = e0 * inv; attw[ao + 1] = e1 * inv;
        attw[ao + 2] = e2 * inv; attw[ao + 3] = e3 * inv;
    }
}

// ---------------------------------------------------------------------------
// Counting-sort the candidate points by 16^3 cell (per batch) -> spatial
// locality for the groups-of-8. spts[b][pos] = (x,y,z,bits(orig_idx)).
// ---------------------------------------------------------------------------
__global__ __launch_bounds__(512)
void build_grid_kernel(const float* __restrict__ ipts,
                       float4* __restrict__ spts, int* __restrict__ cellstart) {
    __shared__ int hist[GN3];
    __shared__ int part[512];
    const int b = blockIdx.x;
    const int t = threadIdx.x;
    const float* pb = ipts + (size_t)b * LIN * 3;

#pragma unroll
    for (int k = 0; k < GN3 / 512; ++k) hist[k * 512 + t] = 0;
    __syncthreads();

    int cells[LIN / 512];
#pragma unroll
    for (int k = 0; k < LIN / 512; ++k) {
        int i = k * 512 + t;
        float x = pb[i * 3 + 0], y = pb[i * 3 + 1], z = pb[i * 3 + 2];
        int cx = min(max((int)floorf((x - GX0) * GINV), 0), GN - 1);
        int cy = min(max((int)floorf((y - GX0) * GINV), 0), GN - 1);
        int cz = min(max((int)floorf((z - GX0) * GINV), 0), GN - 1);
        cells[k] = (cz * GN + cy) * GN + cx;
        atomicAdd(&hist[cells[k]], 1);
    }
    __syncthreads();

    int h8[8];
    int sum = 0;
#pragma unroll
    for (int k = 0; k < 8; ++k) { h8[k] = hist[t * 8 + k]; sum += h8[k]; }
    part[t] = sum;
    __syncthreads();
    for (int off = 1; off < 512; off <<= 1) {
        int v = (t >= off) ? part[t - off] : 0;
        __syncthreads();
        part[t] += v;
        __syncthreads();
    }
    int base = part[t] - sum;
    const int cb = b * (GN3 + 1);
#pragma unroll
    for (int k = 0; k < 8; ++k) {
        int c = t * 8 + k;
        cellstart[cb + c] = base;
        hist[c] = base;
        base += h8[k];
    }
    if (t == 511) cellstart[cb + GN3] = LIN;
    __syncthreads();

#pragma unroll
    for (int k = 0; k < LIN / 512; ++k) {
        int i = k * 512 + t;
        float x = pb[i * 3 + 0], y = pb[i * 3 + 1], z = pb[i * 3 + 2];
        int pos = atomicAdd(&hist[cells[k]], 1);
        spts[(size_t)b * LIN + pos] = make_float4(x, y, z, __int_as_float(i));
    }
}

// ---------------------------------------------------------------------------
// Bounding sphere per group of 8 consecutive sorted candidates.
// gsph[b][g] = (cx, cy, cz, r). One thread per group; loads are a fully
// coalesced 8KB sweep per wave. r gets a +1e-4 bump (sqrt rounding safety;
// the knn compare adds GEPS slack on top).
// ---------------------------------------------------------------------------
__global__ __launch_bounds__(512)
void build_gsph_kernel(const float4* __restrict__ spts, float4* __restrict__ gsph) {
    const int b = blockIdx.x;
    const int g = threadIdx.x;           // 0..511
    const float4* sb = spts + (size_t)b * LIN + g * GSZ;
    float4 p[GSZ];
#pragma unroll
    for (int i = 0; i < GSZ; ++i) p[i] = sb[i];
    float xmn = p[0].x, xmx = p[0].x;
    float ymn = p[0].y, ymx = p[0].y;
    float zmn = p[0].z, zmx = p[0].z;
#pragma unroll
    for (int i = 1; i < GSZ; ++i) {
        xmn = fminf(xmn, p[i].x); xmx = fmaxf(xmx, p[i].x);
        ymn = fminf(ymn, p[i].y); ymx = fmaxf(ymx, p[i].y);
        zmn = fminf(zmn, p[i].z); zmx = fmaxf(zmx, p[i].z);
    }
    float cx = 0.5f * (xmn + xmx);
    float cy = 0.5f * (ymn + ymx);
    float cz = 0.5f * (zmn + zmx);
    float r2 = 0.f;
#pragma unroll
    for (int i = 0; i < GSZ; ++i) {
        float dx = p[i].x - cx, dy = p[i].y - cy, dz = p[i].z - cz;
        r2 = fmaxf(r2, fmaf(dz, dz, fmaf(dy, dy, dx * dx)));
    }
    gsph[(size_t)b * NGRP + g] = make_float4(cx, cy, cz, sqrtf(r2) + 1e-4f);
}

// ---------------------------------------------------------------------------
// Group-pruned exact KNN, dense-scan execution (no pointer chasing).
// 4 lanes per sampling point (splits s=0..3, groups s*128..s*128+127):
//   pass 1: exact scan of 512 real candidates (group first-members) ->
//           valid upper bound + tracker head start. Metric & lex-(d,idx)
//           tie rule identical to the passing brute-force rounds.
//   quad-merge ub (shfl), one sqrt -> true-distance bound.
//   mask sweep: 512 group spheres, keep iff d2(center) <= (ub+r)^2 + GEPS
//           (conservative: fp32 err ~1e-6 << 1e-3 slack) -> 4 u32 masks.
//   pass 2: ctz-walk own mask; each surviving group = 8 contiguous float4
//           (one 128B L2 line pair) exact-checked.
// Round-6/7 lesson applied: all hot loops are regular dense scans over
// L1/L2-broadcast data; divergence is data-only (per-lane masks).
// Grid: NPTS*4 threads = 4096 waves = 4/SIMD (round-4's proven occupancy).
// ---------------------------------------------------------------------------
__global__ __launch_bounds__(256)
void knn_group_kernel(const float* __restrict__ loc, const float4* __restrict__ spts,
                      const float4* __restrict__ gsph, int* __restrict__ idx) {
    const int tid = blockIdx.x * 256 + threadIdx.x;
    const int gq  = tid >> 2;            // sampling point [0, NPTS)
    const int s   = tid & 3;             // split
    const int b   = gq >> 15;            // 32768 points per batch

    const float sx = loc[(size_t)gq * 3 + 0];
    const float sy = loc[(size_t)gq * 3 + 1];
    const float sz = loc[(size_t)gq * 3 + 2];
    const float sx2 = -2.f * sx, sy2 = -2.f * sy, sz2 = -2.f * sz;
    const float ssq = fmaf(sz, sz, fmaf(sy, sy, sx * sx));

    const float4* sb = spts + (size_t)b * LIN;
    const float4* gb = gsph + (size_t)b * NGRP;

    float bd = 1e30f;
    int   bi = 0x7fffffff;

    // pass 1: exact subset scan (first member of each of my 128 groups)
#pragma unroll 4
    for (int g = 0; g < 128; ++g) {
        float4 sp = sb[(((s << 7) + g) << 3)];
        float nrm = fmaf(sp.z, sp.z, fmaf(sp.y, sp.y, sp.x * sp.x));
        float d   = fmaf(sx2, sp.x, fmaf(sy2, sp.y, fmaf(sz2, sp.z, nrm)));
        int   oi  = __float_as_int(sp.w);
        bool take = (d < bd) || (d == bd && oi < bi);
        bi = take ? oi : bi;
        bd = fminf(bd, d);
    }

    // quad-merge upper bound; metric is d_true^2 - ssq, so add ssq back
    float u = bd;
    u = fminf(u, __shfl_xor(u, 1));
    u = fminf(u, __shfl_xor(u, 2));
    const float ub = sqrtf(fmaxf(u + ssq, 0.f));

    // mask sweep over my 128 group spheres
    unsigned mw0 = 0, mw1 = 0, mw2 = 0, mw3 = 0;
#pragma unroll
    for (int w = 0; w < 4; ++w) {
        unsigned mm = 0;
        for (int k = 0; k < 32; ++k) {
            float4 gs = gb[(s << 7) + (w << 5) + k];
            float dx = gs.x - sx, dy = gs.y - sy, dz = gs.z - sz;
            float d2c = fmaf(dz, dz, fmaf(dy, dy, dx * dx));
            float thr = ub + gs.w;
            if (d2c <= fmaf(thr, thr, GEPS)) mm |= (1u << k);
        }
        if (w == 0) mw0 = mm; else if (w == 1) mw1 = mm;
        else if (w == 2) mw2 = mm; else mw3 = mm;
    }

    // pass 2: exact-check surviving groups (8 contiguous float4 each)
#pragma unroll
    for (int w = 0; w < 4; ++w) {
        unsigned mm = (w == 0) ? mw0 : (w == 1) ? mw1 : (w == 2) ? mw2 : mw3;
        while (mm) {
            int k = __builtin_ctz(mm);
            mm &= mm - 1;
            int j0 = ((s << 7) + (w << 5) + k) << 3;
#pragma unroll
            for (int jj = 0; jj < GSZ; ++jj) {
                float4 sp = sb[j0 + jj];
                float nrm = fmaf(sp.z, sp.z, fmaf(sp.y, sp.y, sp.x * sp.x));
                float d   = fmaf(sx2, sp.x, fmaf(sy2, sp.y, fmaf(sz2, sp.z, nrm)));
                int   oi  = __float_as_int(sp.w);
                bool take = (d < bd) || (d == bd && oi < bi);
                bi = take ? oi : bi;
                bd = fminf(bd, d);
            }
        }
    }

    // final quad lex-merge -> global first-min (matches jnp.argmin)
    {
        float od = __shfl_xor(bd, 1); int oi = __shfl_xor(bi, 1);
        bool t1 = (od < bd) || (od == bd && oi < bi);
        bd = t1 ? od : bd; bi = t1 ? oi : bi;
        od = __shfl_xor(bd, 2); oi = __shfl_xor(bi, 2);
        bool t2 = (od < bd) || (od == bd && oi < bi);
        bd = t2 ? od : bd; bi = t2 ? oi : bi;
    }
    if (s == 0) idx[gq] = bi;
}

// ---------------------------------------------------------------------------
// blend_gemm: out1_m = (sum_p attw_p * inp[idx_p]) @ Wv_m^T   (per head m)
// sum_p attw = 1 linearity: 16.8M-MAC blend + 134M-MAC thin GEMM replaces
// the 537M-MAC value GEMM + gather. part[ks][((m*NROW+bq)*32+d)]
// ---------------------------------------------------------------------------
__global__ __launch_bounds__(256)
void blend_gemm_kernel(const float* __restrict__ inp, const float* __restrict__ attw,
                       const int* __restrict__ idx,
                       const float* __restrict__ Wv, float* __restrict__ part) {
    __shared__ float Ab[128][132];   // blended rows, k-major, swizzled
    __shared__ float Bs[32][132];    // Wv_m half, k-major, swizzled
    __shared__ int   ids[128][4];
    __shared__ float ats[128][4];
    const int t  = threadIdx.x;
    const int rb = blockIdx.x * 128;     // bq base
    const int m  = blockIdx.y;
    const int ks = blockIdx.z;
    const int k0 = ks * 128;

    if (t < 128) {
        size_t base = ((size_t)(rb + t) * MH + m) * NP;
#pragma unroll
        for (int p = 0; p < NP; ++p) {
            ids[t][p] = idx[base + p];
            ats[t][p] = attw[base + p];
        }
    }
#pragma unroll
    for (int pass = 0; pass < 4; ++pass) {
        int u  = pass * 256 + t;
        int nn = u >> 5;                 // 0..31
        int cg = (u & 31) * 4;           // 0..124
        float4 w = *reinterpret_cast<const float4*>(Wv + (size_t)(m * 32 + nn) * CH + k0 + cg);
        *reinterpret_cast<float4*>(&Bs[nn][cg ^ SWZ(nn)]) = w;
    }
    __syncthreads();

#pragma unroll
    for (int pass = 0; pass < 16; ++pass) {
        int u   = pass * 256 + t;
        int row = u >> 5;                // 0..127
        int cg  = (u & 31) * 4;          // coalesced 512B per row-group
        int bq  = rb + row;
        const float* ib = inp + ((size_t)(bq >> 10) * LIN) * CH + k0 + cg;
        float4 a = {0.f, 0.f, 0.f, 0.f};
#pragma unroll
        for (int p = 0; p < NP; ++p) {
            float4 v = *reinterpret_cast<const float4*>(ib + (size_t)ids[row][p] * CH);
            float w = ats[row][p];
            a.x = fmaf(w, v.x, a.x); a.y = fmaf(w, v.y, a.y);
            a.z = fmaf(w, v.z, a.z); a.w = fmaf(w, v.w, a.w);
        }
        *reinterpret_cast<float4*>(&Ab[row][cg ^ SWZ(row)]) = a;
    }
    __syncthreads();

    const int ty = t >> 3;               // 0..31 -> rows ty*4..
    const int tx = t & 7;                // 0..7  -> cols tx*4..
    const int sA = SWZ(ty * 4);
    const int sB = SWZ(tx * 4);
    float acc[4][4] = {};
    for (int k = 0; k < 128; k += 4) {
        float4 a[4], bb[4];
#pragma unroll
        for (int i = 0; i < 4; ++i)
            a[i] = *reinterpret_cast<const float4*>(&Ab[ty * 4 + i][k ^ sA]);
#pragma unroll
        for (int j = 0; j < 4; ++j)
            bb[j] = *reinterpret_cast<const float4*>(&Bs[tx * 4 + j][k ^ sB]);
#pragma unroll
        for (int i = 0; i < 4; ++i)
#pragma unroll
            for (int j = 0; j < 4; ++j)
                acc[i][j] = fmaf(a[i].x, bb[j].x, fmaf(a[i].y, bb[j].y,
                             fmaf(a[i].z, bb[j].z, fmaf(a[i].w, bb[j].w, acc[i][j]))));
    }
#pragma unroll
    for (int i = 0; i < 4; ++i) {
        int bq = rb + ty * 4 + i;
        float4 c = {acc[i][0], acc[i][1], acc[i][2], acc[i][3]};
        *reinterpret_cast<float4*>(part + ((size_t)ks * MH * NROW + (size_t)m * NROW + bq) * 32 + tx * 4) = c;
    }
}

// ---------------------------------------------------------------------------
// out_gemm: out = (part0 + part1 + bv) @ Wo^T + bo   (2048 x 256, K=256)
// 64x32 tiles -> grid (32,8) = 256 blocks.
// ---------------------------------------------------------------------------
__global__ __launch_bounds__(256)
void out_gemm_kernel(const float* __restrict__ part, const float* __restrict__ bv,
                     const float* __restrict__ Wo, const float* __restrict__ bo,
                     float* __restrict__ out) {
    __shared__ float Ab[64][260];
    __shared__ float Bs[32][260];
    const int t  = threadIdx.x;
    const int rb = blockIdx.x * 64;
    const int nb = blockIdx.y * 32;

#pragma unroll
    for (int pass = 0; pass < 16; ++pass) {
        int u   = pass * 256 + t;
        int row = u >> 6;                // 0..63
        int cg  = (u & 63) * 4;          // 0..252
        int bq  = rb + row;
        int mm  = cg >> 5, d = cg & 31;
        size_t pi = ((size_t)mm * NROW + bq) * 32 + d;
        float4 v0 = *reinterpret_cast<const float4*>(part + pi);
        float4 v1 = *reinterpret_cast<const float4*>(part + (size_t)MH * NROW * 32 + pi);
        float4 bb = *reinterpret_cast<const float4*>(bv + cg);
        float4 a  = {v0.x + v1.x + bb.x, v0.y + v1.y + bb.y,
                     v0.z + v1.z + bb.z, v0.w + v1.w + bb.w};
        *reinterpret_cast<float4*>(&Ab[row][cg ^ SWZ(row)]) = a;
    }
#pragma unroll
    for (int pass = 0; pass < 8; ++pass) {
        int u  = pass * 256 + t;
        int nn = u >> 6;                 // 0..31
        int cg = (u & 63) * 4;
        float4 w = *reinterpret_cast<const float4*>(Wo + (size_t)(nb + nn) * CH + cg);
        *reinterpret_cast<float4*>(&Bs[nn][cg ^ SWZ(nn)]) = w;
    }
    __syncthreads();

    const int ty = t >> 3;               // 0..31 -> rows ty*2..
    const int tx = t & 7;                // 0..7  -> cols tx*4..
    const int sA = SWZ(ty * 2);
    const int sB = SWZ(tx * 4);
    float acc[2][4] = {};
    for (int k = 0; k < 256; k += 4) {
        float4 a[2], bb[4];
#pragma unroll
        for (int i = 0; i < 2; ++i)
            a[i] = *reinterpret_cast<const float4*>(&Ab[ty * 2 + i][k ^ sA]);
#pragma unroll
        for (int j = 0; j < 4; ++j)
            bb[j] = *reinterpret_cast<const float4*>(&Bs[tx * 4 + j][k ^ sB]);
#pragma unroll
        for (int i = 0; i < 2; ++i)
#pragma unroll
            for (int j = 0; j < 4; ++j)
                acc[i][j] = fmaf(a[i].x, bb[j].x, fmaf(a[i].y, bb[j].y,
                             fmaf(a[i].z, bb[j].z, fmaf(a[i].w, bb[j].w, acc[i][j]))));
    }
#pragma unroll
    for (int i = 0; i < 2; ++i) {
        int bq = rb + ty * 2 + i;
        int n  = nb + tx * 4;
        float4 c = {acc[i][0] + bo[n + 0], acc[i][1] + bo[n + 1],
                    acc[i][2] + bo[n + 2], acc[i][3] + bo[n + 3]};
        *reinterpret_cast<float4*>(out + (size_t)bq * CH + n) = c;
    }
}

// ---------------------------------------------------------------------------
extern "C" void kernel_launch(void* const* d_in, const int* in_sizes, int n_in,
                              void* d_out, int out_size, void* d_ws, size_t ws_size,
                              hipStream_t stream) {
    const float* query = (const float*)d_in[0];
    const float* qpts  = (const float*)d_in[1];
    const float* inp   = (const float*)d_in[2];
    const float* ipts  = (const float*)d_in[3];
    const float* Wv    = (const float*)d_in[4];
    const float* bv    = (const float*)d_in[5];
    const float* Ws    = (const float*)d_in[6];
    const float* bs    = (const float*)d_in[7];
    const float* Wa    = (const float*)d_in[8];
    const float* ba    = (const float*)d_in[9];
    const float* Wo    = (const float*)d_in[10];
    const float* bo    = (const float*)d_in[11];
    float* out = (float*)d_out;

    // workspace layout (~5.6 MB); every buffer fully overwritten each call
    float*  ws        = (float*)d_ws;
    float*  loc       = ws;                                  // NPTS*3 f
    float*  attw      = loc + (size_t)NPTS * 3;              // NPTS f
    float*  part      = attw + (size_t)NPTS;                 // 2*MH*NROW*32 f
    float4* spts      = (float4*)(part + (size_t)2 * MH * NROW * 32); // B*LIN f4
    float4* gsph      = spts + (size_t)B_ * LIN;             // B*NGRP f4
    int*    idx       = (int*)(gsph + (size_t)B_ * NGRP);    // NPTS i
    int*    cellstart = idx + (size_t)NPTS;                  // B*(GN3+1) i

    // 1. spatial counting sort (locality for groups-of-8)
    build_grid_kernel<<<B_, 512, 0, stream>>>(ipts, spts, cellstart);
    // 2. per-group bounding spheres
    build_gsph_kernel<<<B_, 512, 0, stream>>>(spts, gsph);
    // 3. S-path GEMM -> sampling locations + softmax weights
    gemm_s_fused<<<NROW / 32, 256, 0, stream>>>(query, Ws, bs, Wa, ba, qpts,
                                                loc, attw);
    // 4. group-pruned exact KNN (dense scans only; ~2.5-3x work cut vs r4)
    knn_group_kernel<<<NPTS * 4 / 256, 256, 0, stream>>>(loc, spts, gsph, idx);
    // 5. gather-blend + per-head value GEMM (134M MAC)
    blend_gemm_kernel<<<dim3(NROW / 128, MH, 2), 256, 0, stream>>>(
        inp, attw, idx, Wv, part);
    // 6. output GEMM, merging K-halves + value bias (134M MAC)
    out_gemm_kernel<<<dim3(NROW / 64, CH / 32), 256, 0, stream>>>(
        part, bv, Wo, bo, out);
}

// Round 9
// 239.176 us; speedup vs baseline: 1.6593x; 1.3399x over previous
//
#include <hip/hip_runtime.h>

#define B_   2
#define LQ   1024
#define LIN  4096
#define CH   256
#define MH   8
#define NP   4
#define NROW (B_ * LQ)                  // 2048 (b,q) rows
#define NPTS (NROW * MH * NP)           // 65536 sampling points

#define KSLICES 8
#define KSLEN   (LIN / KSLICES)         // 512 candidates per slice

// LDS row-swizzle for the GEMM kernels (<=2-way bank aliasing on b128 frags)
#define SWZ(r) ((((r) >> 2) & 7) << 2)

// ---------------------------------------------------------------------------
// Fused S-path: S = query @ [Ws;Wa]^T + [bs;ba] (2048 x 128), then directly
//   loc[b,q,m,p,:] = query_points + S[row][m*12+p*3+e]
//   attw[b,q,m,p]  = softmax_p(S[row][96+m*4+p])
//   keys[b,q,m,p]  = u64 max (argmin identity for the knn atomicMin pass)
// 32 rows x 128 cols per block -> 64 blocks. 256 threads, 2x8 micro, BK=16.
// ---------------------------------------------------------------------------
__global__ __launch_bounds__(256)
void gemm_s_fused(const float* __restrict__ query,
                  const float* __restrict__ Ws, const float* __restrict__ bs,
                  const float* __restrict__ Wa, const float* __restrict__ ba,
                  const float* __restrict__ qpts,
                  float* __restrict__ loc, float* __restrict__ attw,
                  unsigned long long* __restrict__ keys) {
    __shared__ float As[16][32];
    __shared__ float Bs[16][128];
    __shared__ float Ss[32][132];
    const int tid = threadIdx.x;
    const int rowbase = blockIdx.x * 32;
    const int tx = tid & 15;          // col group (8 cols)
    const int ty = tid >> 4;          // row group (2 rows)

    const int lr  = tid >> 3;         // A-staging row 0..31
    const int lka = (tid & 7) * 2;    // A-staging k (float2)
    const float* Ap = query + (size_t)(rowbase + lr) * CH + lka;
    const int n   = tid >> 1;         // B-staging weight row
    const int lkb = (tid & 1) * 8;
    const float* Wrow = ((n < 96) ? (Ws + (size_t)n * CH)
                                  : (Wa + (size_t)(n - 96) * CH)) + lkb;
    float bj[8];
#pragma unroll
    for (int j = 0; j < 8; ++j) {
        int col = tx * 8 + j;
        bj[j] = (col < 96) ? bs[col] : ba[col - 96];
    }

    float2 a0 = *reinterpret_cast<const float2*>(Ap);
    float4 b0 = *reinterpret_cast<const float4*>(Wrow);
    float4 b1 = *reinterpret_cast<const float4*>(Wrow + 4);

    float acc[2][8] = {};
    for (int k0 = 0; k0 < CH; k0 += 16) {
        __syncthreads();
        As[lka + 0][lr] = a0.x; As[lka + 1][lr] = a0.y;
        Bs[lkb + 0][n] = b0.x; Bs[lkb + 1][n] = b0.y;
        Bs[lkb + 2][n] = b0.z; Bs[lkb + 3][n] = b0.w;
        Bs[lkb + 4][n] = b1.x; Bs[lkb + 5][n] = b1.y;
        Bs[lkb + 6][n] = b1.z; Bs[lkb + 7][n] = b1.w;
        __syncthreads();
        if (k0 + 16 < CH) {
            a0 = *reinterpret_cast<const float2*>(Ap + k0 + 16);
            b0 = *reinterpret_cast<const float4*>(Wrow + k0 + 16);
            b1 = *reinterpret_cast<const float4*>(Wrow + k0 + 20);
        }
#pragma unroll
        for (int k = 0; k < 16; ++k) {
            float2 a  = *reinterpret_cast<const float2*>(&As[k][ty << 1]);
            float4 v0 = *reinterpret_cast<const float4*>(&Bs[k][tx * 8]);
            float4 v1 = *reinterpret_cast<const float4*>(&Bs[k][tx * 8 + 4]);
            float ar[2] = {a.x, a.y};
            float br[8] = {v0.x, v0.y, v0.z, v0.w, v1.x, v1.y, v1.z, v1.w};
#pragma unroll
            for (int i = 0; i < 2; ++i)
#pragma unroll
                for (int j = 0; j < 8; ++j)
                    acc[i][j] = fmaf(ar[i], br[j], acc[i][j]);
        }
    }

    __syncthreads();
#pragma unroll
    for (int i = 0; i < 2; ++i)
#pragma unroll
        for (int j = 0; j < 8; ++j)
            Ss[ty * 2 + i][tx * 8 + j] = acc[i][j] + bj[j];
    __syncthreads();

    {   // epilogue: 256 units = 32 rows x 8 heads
        int row = tid >> 3;
        int m   = tid & 7;
        int r   = rowbase + row;
        const float* Sr = Ss[row];
        float q0 = qpts[r * 3 + 0], q1 = qpts[r * 3 + 1], q2 = qpts[r * 3 + 2];
#pragma unroll
        for (int p = 0; p < NP; ++p) {
            size_t o = ((size_t)(r * MH + m) * NP + p) * 3;
            loc[o + 0] = q0 + Sr[m * 12 + p * 3 + 0];
            loc[o + 1] = q1 + Sr[m * 12 + p * 3 + 1];
            loc[o + 2] = q2 + Sr[m * 12 + p * 3 + 2];
        }
        float l0 = Sr[96 + m * 4 + 0], l1 = Sr[96 + m * 4 + 1];
        float l2 = Sr[96 + m * 4 + 2], l3 = Sr[96 + m * 4 + 3];
        float mx = fmaxf(fmaxf(l0, l1), fmaxf(l2, l3));
        float e0 = expf(l0 - mx), e1 = expf(l1 - mx);
        float e2 = expf(l2 - mx), e3 = expf(l3 - mx);
        float inv = 1.0f / (e0 + e1 + e2 + e3);
        size_t ao = (size_t)(r * MH + m) * NP;
        attw[ao + 0] = e0 * inv; attw[ao + 1] = e1 * inv;
        attw[ao + 2] = e2 * inv; attw[ao + 3] = e3 * inv;
        unsigned long long* kp = keys + ao;
        kp[0] = kp[1] = kp[2] = kp[3] = 0xFFFFFFFFFFFFFFFFull;
    }
}

// ---------------------------------------------------------------------------
// prep: cpts[i] = (x, y, z, |v|^2) in ORIGINAL order (index = position, so
// the knn scan-order tie rule matches jnp.argmin exactly).
// Thread t handles 4 candidates = 12 contiguous floats (3 aligned float4).
// ---------------------------------------------------------------------------
__global__ __launch_bounds__(256)
void prep_pts_kernel(const float* __restrict__ ipts, float4* __restrict__ cpts) {
    int t = blockIdx.x * 256 + threadIdx.x;      // 0 .. B*LIN/4-1
    const float* sp = ipts + (size_t)t * 12;
    float4 u0 = *reinterpret_cast<const float4*>(sp + 0);
    float4 u1 = *reinterpret_cast<const float4*>(sp + 4);
    float4 u2 = *reinterpret_cast<const float4*>(sp + 8);
    float xs[4] = {u0.x, u0.w, u1.z, u2.y};
    float ys[4] = {u0.y, u1.x, u1.w, u2.z};
    float zs[4] = {u0.z, u1.y, u2.x, u2.w};
#pragma unroll
    for (int i = 0; i < 4; ++i) {
        float nrm = fmaf(zs[i], zs[i], fmaf(ys[i], ys[i], xs[i] * xs[i]));
        cpts[(size_t)t * 4 + i] = make_float4(xs[i], ys[i], zs[i], nrm);
    }
}

// ---------------------------------------------------------------------------
// Scalar-broadcast brute-force KNN. Each lane owns ONE sampling point;
// the candidate stream is wave-uniform (const __restrict__, block-uniform
// index) -> compiler scalarizes to s_load + SGPR index counters, leaving a
// pure-VALU inner chain per pair: mul, fmac, fmac, add, cmp, cndmask, min
// (7 ops; each reads <=1 SGPR). No LDS, no vector loads, tiny VGPR count.
// Grid (NPTS/256, 8 slices) = 8192 waves = 32 waves/CU for latency hiding
// (r6/r7/r8 lesson: global candidate reads must be latency-hidden by TLP).
// Two trackers (even/odd scan order, strict <) + lex merge + packed-key
// atomicMin across slices = exact jnp.argmin first-min semantics (r3/r4
// proven). d metric = |v|^2 - 2 s.v, same as all passing rounds.
// ---------------------------------------------------------------------------
__global__ __launch_bounds__(256)
void knn_scalar_kernel(const float* __restrict__ loc,
                       const float4* __restrict__ cpts,
                       unsigned long long* __restrict__ keys) {
    const int gq    = blockIdx.x * 256 + threadIdx.x;   // sampling point
    const int slice = blockIdx.y;
    const int b     = gq >> 15;                          // 32768 points/batch
    const int sbase = slice * KSLEN;                     // uniform

    const float sx = loc[(size_t)gq * 3 + 0];
    const float sy = loc[(size_t)gq * 3 + 1];
    const float sz = loc[(size_t)gq * 3 + 2];
    const float sx2 = -2.f * sx, sy2 = -2.f * sy, sz2 = -2.f * sz;

    const float4* cb = cpts + (size_t)b * LIN + sbase;   // uniform pointer

    float bd0 = 1e30f, bd1 = 1e30f;
    int   bi0 = sbase, bi1 = sbase;

#pragma unroll 4
    for (int j = 0; j < KSLEN; j += 2) {
        float4 p0 = cb[j];          // wave-uniform loads -> s_load
        float4 p1 = cb[j + 1];
        // each op reads at most one scalar operand (1-SGPR rule)
        float t0 = sx2 * p0.x;
        t0 = fmaf(sy2, p0.y, t0);
        t0 = fmaf(sz2, p0.z, t0);
        float d0 = t0 + p0.w;
        float t1 = sx2 * p1.x;
        t1 = fmaf(sy2, p1.y, t1);
        t1 = fmaf(sz2, p1.z, t1);
        float d1 = t1 + p1.w;
        bool a0 = d0 < bd0;                 // strict <, ascending scan ->
        bi0 = a0 ? (sbase + j) : bi0;       // first-min within tracker
        bd0 = fminf(bd0, d0);
        bool a1 = d1 < bd1;
        bi1 = a1 ? (sbase + j + 1) : bi1;
        bd1 = fminf(bd1, d1);
    }

    // lex (d, idx) tracker merge -> slice first-min
    float d = bd0; int ix = bi0;
    if (bd1 < d || (bd1 == d && bi1 < ix)) { d = bd1; ix = bi1; }

    // order-preserving float->uint (d can be negative), packed-key atomicMin:
    // equal-d ties resolve to lowest idx regardless of arrival order.
    unsigned int ub  = __float_as_uint(d);
    unsigned int k32 = ub ^ (((unsigned int)((int)ub >> 31)) | 0x80000000u);
    unsigned long long key = ((unsigned long long)k32 << 32) | (unsigned int)ix;
    atomicMin(&keys[gq], key);
}

// ---------------------------------------------------------------------------
// blend_gemm: out1_m = (sum_p attw_p * inp[idx_p]) @ Wv_m^T   (per head m)
// sum_p attw = 1 linearity: 16.8M-MAC blend + 134M-MAC thin GEMM replaces
// the 537M-MAC value GEMM + gather. part[ks][((m*NROW+bq)*32+d)]
// ---------------------------------------------------------------------------
__global__ __launch_bounds__(256)
void blend_gemm_kernel(const float* __restrict__ inp, const float* __restrict__ attw,
                       const unsigned long long* __restrict__ keys,
                       const float* __restrict__ Wv, float* __restrict__ part) {
    __shared__ float Ab[128][132];   // blended rows, k-major, swizzled
    __shared__ float Bs[32][132];    // Wv_m half, k-major, swizzled
    __shared__ int   ids[128][4];
    __shared__ float ats[128][4];
    const int t  = threadIdx.x;
    const int rb = blockIdx.x * 128;     // bq base
    const int m  = blockIdx.y;
    const int ks = blockIdx.z;
    const int k0 = ks * 128;

    if (t < 128) {
        size_t base = ((size_t)(rb + t) * MH + m) * NP;
#pragma unroll
        for (int p = 0; p < NP; ++p) {
            ids[t][p] = (int)(keys[base + p] & 0xFFFFFFFFull);
            ats[t][p] = attw[base + p];
        }
    }
#pragma unroll
    for (int pass = 0; pass < 4; ++pass) {
        int u  = pass * 256 + t;
        int nn = u >> 5;                 // 0..31
        int cg = (u & 31) * 4;           // 0..124
        float4 w = *reinterpret_cast<const float4*>(Wv + (size_t)(m * 32 + nn) * CH + k0 + cg);
        *reinterpret_cast<float4*>(&Bs[nn][cg ^ SWZ(nn)]) = w;
    }
    __syncthreads();

#pragma unroll
    for (int pass = 0; pass < 16; ++pass) {
        int u   = pass * 256 + t;
        int row = u >> 5;                // 0..127
        int cg  = (u & 31) * 4;          // coalesced 512B per row-group
        int bq  = rb + row;
        const float* ib = inp + ((size_t)(bq >> 10) * LIN) * CH + k0 + cg;
        float4 a = {0.f, 0.f, 0.f, 0.f};
#pragma unroll
        for (int p = 0; p < NP; ++p) {
            float4 v = *reinterpret_cast<const float4*>(ib + (size_t)ids[row][p] * CH);
            float w = ats[row][p];
            a.x = fmaf(w, v.x, a.x); a.y = fmaf(w, v.y, a.y);
            a.z = fmaf(w, v.z, a.z); a.w = fmaf(w, v.w, a.w);
        }
        *reinterpret_cast<float4*>(&Ab[row][cg ^ SWZ(row)]) = a;
    }
    __syncthreads();

    const int ty = t >> 3;               // 0..31 -> rows ty*4..
    const int tx = t & 7;                // 0..7  -> cols tx*4..
    const int sA = SWZ(ty * 4);
    const int sB = SWZ(tx * 4);
    float acc[4][4] = {};
    for (int k = 0; k < 128; k += 4) {
        float4 a[4], bb[4];
#pragma unroll
        for (int i = 0; i < 4; ++i)
            a[i] = *reinterpret_cast<const float4*>(&Ab[ty * 4 + i][k ^ sA]);
#pragma unroll
        for (int j = 0; j < 4; ++j)
            bb[j] = *reinterpret_cast<const float4*>(&Bs[tx * 4 + j][k ^ sB]);
#pragma unroll
        for (int i = 0; i < 4; ++i)
#pragma unroll
            for (int j = 0; j < 4; ++j)
                acc[i][j] = fmaf(a[i].x, bb[j].x, fmaf(a[i].y, bb[j].y,
                             fmaf(a[i].z, bb[j].z, fmaf(a[i].w, bb[j].w, acc[i][j]))));
    }
#pragma unroll
    for (int i = 0; i < 4; ++i) {
        int bq = rb + ty * 4 + i;
        float4 c = {acc[i][0], acc[i][1], acc[i][2], acc[i][3]};
        *reinterpret_cast<float4*>(part + ((size_t)ks * MH * NROW + (size_t)m * NROW + bq) * 32 + tx * 4) = c;
    }
}

// ---------------------------------------------------------------------------
// out_gemm: out = (part0 + part1 + bv) @ Wo^T + bo   (2048 x 256, K=256)
// 64x32 tiles -> grid (32,8) = 256 blocks.
// ---------------------------------------------------------------------------
__global__ __launch_bounds__(256)
void out_gemm_kernel(const float* __restrict__ part, const float* __restrict__ bv,
                     const float* __restrict__ Wo, const float* __restrict__ bo,
                     float* __restrict__ out) {
    __shared__ float Ab[64][260];
    __shared__ float Bs[32][260];
    const int t  = threadIdx.x;
    const int rb = blockIdx.x * 64;
    const int nb = blockIdx.y * 32;

#pragma unroll
    for (int pass = 0; pass < 16; ++pass) {
        int u   = pass * 256 + t;
        int row = u >> 6;                // 0..63
        int cg  = (u & 63) * 4;          // 0..252
        int bq  = rb + row;
        int mm  = cg >> 5, d = cg & 31;
        size_t pi = ((size_t)mm * NROW + bq) * 32 + d;
        float4 v0 = *reinterpret_cast<const float4*>(part + pi);
        float4 v1 = *reinterpret_cast<const float4*>(part + (size_t)MH * NROW * 32 + pi);
        float4 bb = *reinterpret_cast<const float4*>(bv + cg);
        float4 a  = {v0.x + v1.x + bb.x, v0.y + v1.y + bb.y,
                     v0.z + v1.z + bb.z, v0.w + v1.w + bb.w};
        *reinterpret_cast<float4*>(&Ab[row][cg ^ SWZ(row)]) = a;
    }
#pragma unroll
    for (int pass = 0; pass < 8; ++pass) {
        int u  = pass * 256 + t;
        int nn = u >> 6;                 // 0..31
        int cg = (u & 63) * 4;
        float4 w = *reinterpret_cast<const float4*>(Wo + (size_t)(nb + nn) * CH + cg);
        *reinterpret_cast<float4*>(&Bs[nn][cg ^ SWZ(nn)]) = w;
    }
    __syncthreads();

    const int ty = t >> 3;               // 0..31 -> rows ty*2..
    const int tx = t & 7;                // 0..7  -> cols tx*4..
    const int sA = SWZ(ty * 2);
    const int sB = SWZ(tx * 4);
    float acc[2][4] = {};
    for (int k = 0; k < 256; k += 4) {
        float4 a[2], bb[4];
#pragma unroll
        for (int i = 0; i < 2; ++i)
            a[i] = *reinterpret_cast<const float4*>(&Ab[ty * 2 + i][k ^ sA]);
#pragma unroll
        for (int j = 0; j < 4; ++j)
            bb[j] = *reinterpret_cast<const float4*>(&Bs[tx * 4 + j][k ^ sB]);
#pragma unroll
        for (int i = 0; i < 2; ++i)
#pragma unroll
            for (int j = 0; j < 4; ++j)
                acc[i][j] = fmaf(a[i].x, bb[j].x, fmaf(a[i].y, bb[j].y,
                             fmaf(a[i].z, bb[j].z, fmaf(a[i].w, bb[j].w, acc[i][j]))));
    }
#pragma unroll
    for (int i = 0; i < 2; ++i) {
        int bq = rb + ty * 2 + i;
        int n  = nb + tx * 4;
        float4 c = {acc[i][0] + bo[n + 0], acc[i][1] + bo[n + 1],
                    acc[i][2] + bo[n + 2], acc[i][3] + bo[n + 3]};
        *reinterpret_cast<float4*>(out + (size_t)bq * CH + n) = c;
    }
}

// ---------------------------------------------------------------------------
extern "C" void kernel_launch(void* const* d_in, const int* in_sizes, int n_in,
                              void* d_out, int out_size, void* d_ws, size_t ws_size,
                              hipStream_t stream) {
    const float* query = (const float*)d_in[0];
    const float* qpts  = (const float*)d_in[1];
    const float* inp   = (const float*)d_in[2];
    const float* ipts  = (const float*)d_in[3];
    const float* Wv    = (const float*)d_in[4];
    const float* bv    = (const float*)d_in[5];
    const float* Ws    = (const float*)d_in[6];
    const float* bs    = (const float*)d_in[7];
    const float* Wa    = (const float*)d_in[8];
    const float* ba    = (const float*)d_in[9];
    const float* Wo    = (const float*)d_in[10];
    const float* bo    = (const float*)d_in[11];
    float* out = (float*)d_out;

    // workspace layout (~6 MB); every buffer fully overwritten each call
    float*  ws   = (float*)d_ws;
    float*  loc  = ws;                                   // NPTS*3 f
    float*  attw = loc + (size_t)NPTS * 3;               // NPTS f
    float*  part = attw + (size_t)NPTS;                  // 2*MH*NROW*32 f
    float4* cpts = (float4*)(part + (size_t)2 * MH * NROW * 32);  // B*LIN f4
    unsigned long long* keys =
        (unsigned long long*)(cpts + (size_t)B_ * LIN);  // NPTS u64

    // 1. candidate prep: append |v|^2, original order (index = position)
    prep_pts_kernel<<<B_ * LIN / 4 / 256, 256, 0, stream>>>(ipts, cpts);
    // 2. S-path GEMM -> sampling locations + softmax weights + keys init
    gemm_s_fused<<<NROW / 32, 256, 0, stream>>>(query, Ws, bs, Wa, ba, qpts,
                                                loc, attw, keys);
    // 3. scalar-broadcast brute-force KNN (8 slices, 32 waves/CU,
    //    packed-key atomicMin merge; exact first-min semantics)
    knn_scalar_kernel<<<dim3(NPTS / 256, KSLICES), 256, 0, stream>>>(
        loc, cpts, keys);
    // 4. gather-blend + per-head value GEMM (134M MAC)
    blend_gemm_kernel<<<dim3(NROW / 128, MH, 2), 256, 0, stream>>>(
        inp, attw, keys, Wv, part);
    // 5. output GEMM, merging K-halves + value bias (134M MAC)
    out_gemm_kernel<<<dim3(NROW / 64, CH / 32), 256, 0, stream>>>(
        part, bv, Wo, bo, out);
}

// Round 11
// 229.709 us; speedup vs baseline: 1.7277x; 1.0412x over previous
//
#include <hip/hip_runtime.h>

#define B_   2
#define LQ   1024
#define LIN  4096
#define CH   256
#define MH   8
#define NP   4
#define NROW (B_ * LQ)                  // 2048 (b,q) rows
#define NPTS (NROW * MH * NP)           // 65536 sampling points

// spatial sort grid: 16^3 cells over [-5.12, 5.12], z-major -> 16 z-slabs
#define GN   16
#define GN3  (GN * GN * GN)
#define GH   0.64f
#define GX0  (-5.12f)
#define GINV 1.5625f
#define GEPS 1e-3f                      // pruning slack (absolute, squared dist)
#define NSL   16                        // slabs (slices of 256 sorted cands)
#define SLLEN 256

// LDS row-swizzle for the GEMM kernels (<=2-way bank aliasing on b128 frags)
#define SWZ(r) ((((r) >> 2) & 7) << 2)

// ---------------------------------------------------------------------------
// Fused S-path: S = query @ [Ws;Wa]^T + [bs;ba] (2048 x 128), then directly
//   loc[b,q,m,p,:] = query_points + S[row][m*12+p*3+e]
//   attw[b,q,m,p]  = softmax_p(S[row][96+m*4+p])
// 32 rows x 128 cols per block -> 64 blocks. 256 threads, 2x8 micro, BK=16.
// ---------------------------------------------------------------------------
__global__ __launch_bounds__(256)
void gemm_s_fused(const float* __restrict__ query,
                  const float* __restrict__ Ws, const float* __restrict__ bs,
                  const float* __restrict__ Wa, const float* __restrict__ ba,
                  const float* __restrict__ qpts,
                  float* __restrict__ loc, float* __restrict__ attw) {
    __shared__ float As[16][32];
    __shared__ float Bs[16][128];
    __shared__ float Ss[32][132];
    const int tid = threadIdx.x;
    const int rowbase = blockIdx.x * 32;
    const int tx = tid & 15;          // col group (8 cols)
    const int ty = tid >> 4;          // row group (2 rows)

    const int lr  = tid >> 3;         // A-staging row 0..31
    const int lka = (tid & 7) * 2;    // A-staging k (float2)
    const float* Ap = query + (size_t)(rowbase + lr) * CH + lka;
    const int n   = tid >> 1;         // B-staging weight row
    const int lkb = (tid & 1) * 8;
    const float* Wrow = ((n < 96) ? (Ws + (size_t)n * CH)
                                  : (Wa + (size_t)(n - 96) * CH)) + lkb;
    float bj[8];
#pragma unroll
    for (int j = 0; j < 8; ++j) {
        int col = tx * 8 + j;
        bj[j] = (col < 96) ? bs[col] : ba[col - 96];
    }

    float2 a0 = *reinterpret_cast<const float2*>(Ap);
    float4 b0 = *reinterpret_cast<const float4*>(Wrow);
    float4 b1 = *reinterpret_cast<const float4*>(Wrow + 4);

    float acc[2][8] = {};
    for (int k0 = 0; k0 < CH; k0 += 16) {
        __syncthreads();
        As[lka + 0][lr] = a0.x; As[lka + 1][lr] = a0.y;
        Bs[lkb + 0][n] = b0.x; Bs[lkb + 1][n] = b0.y;
        Bs[lkb + 2][n] = b0.z; Bs[lkb + 3][n] = b0.w;
        Bs[lkb + 4][n] = b1.x; Bs[lkb + 5][n] = b1.y;
        Bs[lkb + 6][n] = b1.z; Bs[lkb + 7][n] = b1.w;
        __syncthreads();
        if (k0 + 16 < CH) {
            a0 = *reinterpret_cast<const float2*>(Ap + k0 + 16);
            b0 = *reinterpret_cast<const float4*>(Wrow + k0 + 16);
            b1 = *reinterpret_cast<const float4*>(Wrow + k0 + 20);
        }
#pragma unroll
        for (int k = 0; k < 16; ++k) {
            float2 a  = *reinterpret_cast<const float2*>(&As[k][ty << 1]);
            float4 v0 = *reinterpret_cast<const float4*>(&Bs[k][tx * 8]);
            float4 v1 = *reinterpret_cast<const float4*>(&Bs[k][tx * 8 + 4]);
            float ar[2] = {a.x, a.y};
            float br[8] = {v0.x, v0.y, v0.z, v0.w, v1.x, v1.y, v1.z, v1.w};
#pragma unroll
            for (int i = 0; i < 2; ++i)
#pragma unroll
                for (int j = 0; j < 8; ++j)
                    acc[i][j] = fmaf(ar[i], br[j], acc[i][j]);
        }
    }

    __syncthreads();
#pragma unroll
    for (int i = 0; i < 2; ++i)
#pragma unroll
        for (int j = 0; j < 8; ++j)
            Ss[ty * 2 + i][tx * 8 + j] = acc[i][j] + bj[j];
    __syncthreads();

    {   // epilogue: 256 units = 32 rows x 8 heads
        int row = tid >> 3;
        int m   = tid & 7;
        int r   = rowbase + row;
        const float* Sr = Ss[row];
        float q0 = qpts[r * 3 + 0], q1 = qpts[r * 3 + 1], q2 = qpts[r * 3 + 2];
#pragma unroll
        for (int p = 0; p < NP; ++p) {
            size_t o = ((size_t)(r * MH + m) * NP + p) * 3;
            loc[o + 0] = q0 + Sr[m * 12 + p * 3 + 0];
            loc[o + 1] = q1 + Sr[m * 12 + p * 3 + 1];
            loc[o + 2] = q2 + Sr[m * 12 + p * 3 + 2];
        }
        float l0 = Sr[96 + m * 4 + 0], l1 = Sr[96 + m * 4 + 1];
        float l2 = Sr[96 + m * 4 + 2], l3 = Sr[96 + m * 4 + 3];
        float mx = fmaxf(fmaxf(l0, l1), fmaxf(l2, l3));
        float e0 = expf(l0 - mx), e1 = expf(l1 - mx);
        float e2 = expf(l2 - mx), e3 = expf(l3 - mx);
        float inv = 1.0f / (e0 + e1 + e2 + e3);
        size_t ao = (size_t)(r * MH + m) * NP;
        attw[ao + 0] = e0 * inv; attw[ao + 1] = e1 * inv;
        attw[ao + 2] = e2 * inv; attw[ao + 3] = e3 * inv;
    }
}

// ---------------------------------------------------------------------------
// Counting-sort candidates by 16^3 cell (z-major -> sorted order = z-slabs).
// spts[b][pos] = (x,y,z,bits(orig_idx)); cellstart[b][c] = cell range;
// sbox[b][s][0/1] = min/max corner of slab s (256 sorted candidates).
// One block per batch. Sort + scatter body is the round-5-proven kernel
// verbatim; the sbox tail is new.
// ---------------------------------------------------------------------------
__global__ __launch_bounds__(512)
void build_grid_kernel(const float* __restrict__ ipts,
                       float4* __restrict__ spts, int* __restrict__ cellstart,
                       float4* __restrict__ sbox) {
    __shared__ int hist[GN3];
    __shared__ int part[512];
    const int b = blockIdx.x;
    const int t = threadIdx.x;
    const float* pb = ipts + (size_t)b * LIN * 3;

#pragma unroll
    for (int k = 0; k < GN3 / 512; ++k) hist[k * 512 + t] = 0;
    __syncthreads();

    int cells[LIN / 512];
#pragma unroll
    for (int k = 0; k < LIN / 512; ++k) {
        int i = k * 512 + t;
        float x = pb[i * 3 + 0], y = pb[i * 3 + 1], z = pb[i * 3 + 2];
        int cx = min(max((int)floorf((x - GX0) * GINV), 0), GN - 1);
        int cy = min(max((int)floorf((y - GX0) * GINV), 0), GN - 1);
        int cz = min(max((int)floorf((z - GX0) * GINV), 0), GN - 1);
        cells[k] = (cz * GN + cy) * GN + cx;
        atomicAdd(&hist[cells[k]], 1);
    }
    __syncthreads();

    // exclusive scan over 4096: per-thread serial(8) + Hillis-Steele(512)
    int h8[8];
    int sum = 0;
#pragma unroll
    for (int k = 0; k < 8; ++k) { h8[k] = hist[t * 8 + k]; sum += h8[k]; }
    part[t] = sum;
    __syncthreads();
    for (int off = 1; off < 512; off <<= 1) {
        int v = (t >= off) ? part[t - off] : 0;
        __syncthreads();
        part[t] += v;
        __syncthreads();
    }
    int base = part[t] - sum;
    const int cb = b * (GN3 + 1);
#pragma unroll
    for (int k = 0; k < 8; ++k) {
        int c = t * 8 + k;
        cellstart[cb + c] = base;
        hist[c] = base;                  // becomes the scatter cursor
        base += h8[k];
    }
    if (t == 511) cellstart[cb + GN3] = LIN;
    __syncthreads();

#pragma unroll
    for (int k = 0; k < LIN / 512; ++k) {
        int i = k * 512 + t;
        float x = pb[i * 3 + 0], y = pb[i * 3 + 1], z = pb[i * 3 + 2];
        int pos = atomicAdd(&hist[cells[k]], 1);
        spts[(size_t)b * LIN + pos] = make_float4(x, y, z, __int_as_float(i));
    }
    __syncthreads();   // drains vmem before barrier -> scattered data visible

    // slab bboxes: slab s = sorted positions [s*256, s*256+256)
    {
        int s = t >> 5, u = t & 31;      // 16 slabs x 32 threads
        const float4* p = spts + (size_t)b * LIN + s * SLLEN + u * 8;
        float mnx = 1e30f, mny = 1e30f, mnz = 1e30f;
        float mxx = -1e30f, mxy = -1e30f, mxz = -1e30f;
#pragma unroll
        for (int i = 0; i < 8; ++i) {
            float4 q = p[i];
            mnx = fminf(mnx, q.x); mxx = fmaxf(mxx, q.x);
            mny = fminf(mny, q.y); mxy = fmaxf(mxy, q.y);
            mnz = fminf(mnz, q.z); mxz = fmaxf(mxz, q.z);
        }
#pragma unroll
        for (int m = 1; m < 32; m <<= 1) {   // stays within the 32-half
            mnx = fminf(mnx, __shfl_xor(mnx, m));
            mxx = fmaxf(mxx, __shfl_xor(mxx, m));
            mny = fminf(mny, __shfl_xor(mny, m));
            mxy = fmaxf(mxy, __shfl_xor(mxy, m));
            mnz = fminf(mnz, __shfl_xor(mnz, m));
            mxz = fmaxf(mxz, __shfl_xor(mxz, m));
        }
        if (u == 0) {
            sbox[((size_t)b * NSL + s) * 2 + 0] = make_float4(mnx, mny, mnz, 0.f);
            sbox[((size_t)b * NSL + s) * 2 + 1] = make_float4(mxx, mxy, mxz, 0.f);
        }
    }
}

// ---------------------------------------------------------------------------
// Slab-pruned exact KNN = r4's dense-LDS-scan execution x r7's row locality.
// One wave per (b,q) row (its 32 sampling points are one spatial cluster;
// lane l and l+32 both own point l&31, splitting each slab half/half).
// Per wave: visit the slab containing lane-0's cell FIRST (tight ub), then
// each remaining slab only if any lane's exact box-LB passes:
//   prune iff ALL lanes: LB^2 > best_true^2 + 1e-3  (conservative; a pruned
//   slab's members all exceed the current min by > slack -> can't be the
//   argmin even on ties). Surviving slabs ~2-4 of 16.
// Processing a slab = r4's proven pattern: stage 256 float4 to this wave's
// private LDS slot (4/lane, coalesced), dense scan from LDS (broadcast
// reads, <=2-way aliasing = free), fmaf metric d = |v|^2 - 2 s.v and
// lex-(d, orig_idx) ties -> scan-order independent = jnp.argmin first-min.
// Two trackers/lane (64 cands each) for ILP; in-lane + shfl_xor(32) merge.
// No atomics, no barriers (wave-private LDS), no global hot-loop loads.
// ---------------------------------------------------------------------------
__global__ __launch_bounds__(256)
void knn_slab_kernel(const float* __restrict__ loc,
                     const float4* __restrict__ spts,
                     const int* __restrict__ cellstart,
                     const float4* __restrict__ sbox,
                     int* __restrict__ idx) {
    __shared__ float4 pts[4][SLLEN];     // 16 KB, one slot per wave
    const int wslot = threadIdx.x >> 6;
    const int lane  = threadIdx.x & 63;
    const int l32   = lane & 31;
    const int half  = lane >> 5;
    const int row   = blockIdx.x * 4 + wslot;     // (b,q) row
    const int b     = row >> 10;
    const int gq    = row * 32 + l32;             // sampling point

    const float sx = loc[(size_t)gq * 3 + 0];
    const float sy = loc[(size_t)gq * 3 + 1];
    const float sz = loc[(size_t)gq * 3 + 2];
    const float sx2 = -2.f * sx, sy2 = -2.f * sy, sz2 = -2.f * sz;
    const float ssq = fmaf(sz, sz, fmaf(sy, sy, sx * sx));

    // wave-uniform first slab: the one holding lane-0's cell
    int cx = min(max((int)floorf((sx - GX0) * GINV), 0), GN - 1);
    int cy = min(max((int)floorf((sy - GX0) * GINV), 0), GN - 1);
    int cz = min(max((int)floorf((sz - GX0) * GINV), 0), GN - 1);
    int c0 = (cz * GN + cy) * GN + cx;
    int s0 = min(cellstart[b * (GN3 + 1) + c0] >> 8, NSL - 1);
    s0 = __builtin_amdgcn_readfirstlane(s0);

    const float4* sb = spts + (size_t)b * LIN;
    const float4* bx = sbox + (size_t)b * NSL * 2;

    float bd0 = 1e30f, bd1 = 1e30f;
    int   bi0 = 0x7fffffff, bi1 = 0x7fffffff;

    for (int t = 0; t < NSL; ++t) {
        const int s = (t == 0) ? s0 : (t <= s0 ? t - 1 : t);
        if (t > 0) {   // exact per-lane box LB; skip if ALL lanes prune
            float4 mn = bx[s * 2 + 0];
            float4 mx = bx[s * 2 + 1];
            float dx = fmaxf(fmaxf(mn.x - sx, sx - mx.x), 0.f);
            float dy = fmaxf(fmaxf(mn.y - sy, sy - mx.y), 0.f);
            float dz = fmaxf(fmaxf(mn.z - sz, sz - mx.z), 0.f);
            float lb = fmaf(dx, dx, fmaf(dy, dy, dz * dz));
            float ub = fminf(bd0, bd1) + ssq + GEPS;   // best true^2 + slack
            if (__all(lb > ub)) continue;
        }
        // stage slab s (wave-private slot; in-order wave => no barrier)
#pragma unroll
        for (int i = 0; i < 4; ++i)
            pts[wslot][i * 64 + lane] = sb[s * SLLEN + i * 64 + lane];
        // dense scan: this lane covers [half*128, half*128+128) as 2 trackers
        const int base0 = half * 128, base1 = half * 128 + 64;
#pragma unroll 4
        for (int j = 0; j < 64; ++j) {
            float4 p0 = pts[wslot][base0 + j];
            float4 p1 = pts[wslot][base1 + j];
            float n0 = fmaf(p0.z, p0.z, fmaf(p0.y, p0.y, p0.x * p0.x));
            float n1 = fmaf(p1.z, p1.z, fmaf(p1.y, p1.y, p1.x * p1.x));
            float d0 = fmaf(sx2, p0.x, fmaf(sy2, p0.y, fmaf(sz2, p0.z, n0)));
            float d1 = fmaf(sx2, p1.x, fmaf(sy2, p1.y, fmaf(sz2, p1.z, n1)));
            int   o0 = __float_as_int(p0.w);
            int   o1 = __float_as_int(p1.w);
            bool t0 = (d0 < bd0) || (d0 == bd0 && o0 < bi0);
            bi0 = t0 ? o0 : bi0;
            bd0 = fminf(bd0, d0);
            bool t1 = (d1 < bd1) || (d1 == bd1 && o1 < bi1);
            bi1 = t1 ? o1 : bi1;
            bd1 = fminf(bd1, d1);
        }
    }

    // in-lane tracker merge, then cross-half merge (lex first-min)
    float d = bd0; int ix = bi0;
    if (bd1 < d || (bd1 == d && bi1 < ix)) { d = bd1; ix = bi1; }
    float od = __shfl_xor(d, 32);
    int   oi = __shfl_xor(ix, 32);
    if (od < d || (od == d && oi < ix)) { d = od; ix = oi; }
    if (half == 0) idx[gq] = ix;
}

// ---------------------------------------------------------------------------
// blend_gemm: out1_m = (sum_p attw_p * inp[idx_p]) @ Wv_m^T   (per head m)
// sum_p attw = 1 linearity: 16.8M-MAC blend + 134M-MAC thin GEMM replaces
// the 537M-MAC value GEMM + gather. part[ks][((m*NROW+bq)*32+d)]
// ---------------------------------------------------------------------------
__global__ __launch_bounds__(256)
void blend_gemm_kernel(const float* __restrict__ inp, const float* __restrict__ attw,
                       const int* __restrict__ idx,
                       const float* __restrict__ Wv, float* __restrict__ part) {
    __shared__ float Ab[128][132];   // blended rows, k-major, swizzled
    __shared__ float Bs[32][132];    // Wv_m half, k-major, swizzled
    __shared__ int   ids[128][4];
    __shared__ float ats[128][4];
    const int t  = threadIdx.x;
    const int rb = blockIdx.x * 128;     // bq base
    const int m  = blockIdx.y;
    const int ks = blockIdx.z;
    const int k0 = ks * 128;

    if (t < 128) {
        size_t base = ((size_t)(rb + t) * MH + m) * NP;
#pragma unroll
        for (int p = 0; p < NP; ++p) {
            ids[t][p] = idx[base + p];
            ats[t][p] = attw[base + p];
        }
    }
#pragma unroll
    for (int pass = 0; pass < 4; ++pass) {
        int u  = pass * 256 + t;
        int nn = u >> 5;                 // 0..31
        int cg = (u & 31) * 4;           // 0..124
        float4 w = *reinterpret_cast<const float4*>(Wv + (size_t)(m * 32 + nn) * CH + k0 + cg);
        *reinterpret_cast<float4*>(&Bs[nn][cg ^ SWZ(nn)]) = w;
    }
    __syncthreads();

#pragma unroll
    for (int pass = 0; pass < 16; ++pass) {
        int u   = pass * 256 + t;
        int row = u >> 5;                // 0..127
        int cg  = (u & 31) * 4;          // coalesced 512B per row-group
        int bq  = rb + row;
        const float* ib = inp + ((size_t)(bq >> 10) * LIN) * CH + k0 + cg;
        float4 a = {0.f, 0.f, 0.f, 0.f};
#pragma unroll
        for (int p = 0; p < NP; ++p) {
            float4 v = *reinterpret_cast<const float4*>(ib + (size_t)ids[row][p] * CH);
            float w = ats[row][p];
            a.x = fmaf(w, v.x, a.x); a.y = fmaf(w, v.y, a.y);
            a.z = fmaf(w, v.z, a.z); a.w = fmaf(w, v.w, a.w);
        }
        *reinterpret_cast<float4*>(&Ab[row][cg ^ SWZ(row)]) = a;
    }
    __syncthreads();

    const int ty = t >> 3;               // 0..31 -> rows ty*4..
    const int tx = t & 7;                // 0..7  -> cols tx*4..
    const int sA = SWZ(ty * 4);
    const int sB = SWZ(tx * 4);
    float acc[4][4] = {};
    for (int k = 0; k < 128; k += 4) {
        float4 a[4], bb[4];
#pragma unroll
        for (int i = 0; i < 4; ++i)
            a[i] = *reinterpret_cast<const float4*>(&Ab[ty * 4 + i][k ^ sA]);
#pragma unroll
        for (int j = 0; j < 4; ++j)
            bb[j] = *reinterpret_cast<const float4*>(&Bs[tx * 4 + j][k ^ sB]);
#pragma unroll
        for (int i = 0; i < 4; ++i)
#pragma unroll
            for (int j = 0; j < 4; ++j)
                acc[i][j] = fmaf(a[i].x, bb[j].x, fmaf(a[i].y, bb[j].y,
                             fmaf(a[i].z, bb[j].z, fmaf(a[i].w, bb[j].w, acc[i][j]))));
    }
#pragma unroll
    for (int i = 0; i < 4; ++i) {
        int bq = rb + ty * 4 + i;
        float4 c = {acc[i][0], acc[i][1], acc[i][2], acc[i][3]};
        *reinterpret_cast<float4*>(part + ((size_t)ks * MH * NROW + (size_t)m * NROW + bq) * 32 + tx * 4) = c;
    }
}

// ---------------------------------------------------------------------------
// out_gemm: out = (part0 + part1 + bv) @ Wo^T + bo   (2048 x 256, K=256)
// 64x32 tiles -> grid (32,8) = 256 blocks.
// ---------------------------------------------------------------------------
__global__ __launch_bounds__(256)
void out_gemm_kernel(const float* __restrict__ part, const float* __restrict__ bv,
                     const float* __restrict__ Wo, const float* __restrict__ bo,
                     float* __restrict__ out) {
    __shared__ float Ab[64][260];
    __shared__ float Bs[32][260];
    const int t  = threadIdx.x;
    const int rb = blockIdx.x * 64;
    const int nb = blockIdx.y * 32;

#pragma unroll
    for (int pass = 0; pass < 16; ++pass) {
        int u   = pass * 256 + t;
        int row = u >> 6;                // 0..63
        int cg  = (u & 63) * 4;          // 0..252
        int bq  = rb + row;
        int mm  = cg >> 5, d = cg & 31;
        size_t pi = ((size_t)mm * NROW + bq) * 32 + d;
        float4 v0 = *reinterpret_cast<const float4*>(part + pi);
        float4 v1 = *reinterpret_cast<const float4*>(part + (size_t)MH * NROW * 32 + pi);
        float4 bb = *reinterpret_cast<const float4*>(bv + cg);
        float4 a  = {v0.x + v1.x + bb.x, v0.y + v1.y + bb.y,
                     v0.z + v1.z + bb.z, v0.w + v1.w + bb.w};
        *reinterpret_cast<float4*>(&Ab[row][cg ^ SWZ(row)]) = a;
    }
#pragma unroll
    for (int pass = 0; pass < 8; ++pass) {
        int u  = pass * 256 + t;
        int nn = u >> 6;                 // 0..31
        int cg = (u & 63) * 4;
        float4 w = *reinterpret_cast<const float4*>(Wo + (size_t)(nb + nn) * CH + cg);
        *reinterpret_cast<float4*>(&Bs[nn][cg ^ SWZ(nn)]) = w;
    }
    __syncthreads();

    const int ty = t >> 3;               // 0..31 -> rows ty*2..
    const int tx = t & 7;                // 0..7  -> cols tx*4..
    const int sA = SWZ(ty * 2);
    const int sB = SWZ(tx * 4);
    float acc[2][4] = {};
    for (int k = 0; k < 256; k += 4) {
        float4 a[2], bb[4];
#pragma unroll
        for (int i = 0; i < 2; ++i)
            a[i] = *reinterpret_cast<const float4*>(&Ab[ty * 2 + i][k ^ sA]);
#pragma unroll
        for (int j = 0; j < 4; ++j)
            bb[j] = *reinterpret_cast<const float4*>(&Bs[tx * 4 + j][k ^ sB]);
#pragma unroll
        for (int i = 0; i < 2; ++i)
#pragma unroll
            for (int j = 0; j < 4; ++j)
                acc[i][j] = fmaf(a[i].x, bb[j].x, fmaf(a[i].y, bb[j].y,
                             fmaf(a[i].z, bb[j].z, fmaf(a[i].w, bb[j].w, acc[i][j]))));
    }
#pragma unroll
    for (int i = 0; i < 2; ++i) {
        int bq = rb + ty * 2 + i;
        int n  = nb + tx * 4;
        float4 c = {acc[i][0] + bo[n + 0], acc[i][1] + bo[n + 1],
                    acc[i][2] + bo[n + 2], acc[i][3] + bo[n + 3]};
        *reinterpret_cast<float4*>(out + (size_t)bq * CH + n) = c;
    }
}

// ---------------------------------------------------------------------------
extern "C" void kernel_launch(void* const* d_in, const int* in_sizes, int n_in,
                              void* d_out, int out_size, void* d_ws, size_t ws_size,
                              hipStream_t stream) {
    const float* query = (const float*)d_in[0];
    const float* qpts  = (const float*)d_in[1];
    const float* inp   = (const float*)d_in[2];
    const float* ipts  = (const float*)d_in[3];
    const float* Wv    = (const float*)d_in[4];
    const float* bv    = (const float*)d_in[5];
    const float* Ws    = (const float*)d_in[6];
    const float* bs    = (const float*)d_in[7];
    const float* Wa    = (const float*)d_in[8];
    const float* ba    = (const float*)d_in[9];
    const float* Wo    = (const float*)d_in[10];
    const float* bo    = (const float*)d_in[11];
    float* out = (float*)d_out;

    // workspace layout (~5.7 MB); every buffer fully overwritten each call
    float*  ws        = (float*)d_ws;
    float*  loc       = ws;                                  // NPTS*3 f
    float*  attw      = loc + (size_t)NPTS * 3;              // NPTS f
    float*  part      = attw + (size_t)NPTS;                 // 2*MH*NROW*32 f
    float4* spts      = (float4*)(part + (size_t)2 * MH * NROW * 32); // B*LIN f4
    float4* sbox      = spts + (size_t)B_ * LIN;             // B*NSL*2 f4
    int*    idx       = (int*)(sbox + (size_t)B_ * NSL * 2); // NPTS i
    int*    cellstart = idx + (size_t)NPTS;                  // B*(GN3+1) i

    // 1. spatial counting sort + slab bboxes (independent of 2.)
    build_grid_kernel<<<B_, 512, 0, stream>>>(ipts, spts, cellstart, sbox);
    // 2. S-path GEMM -> sampling locations + softmax weights
    gemm_s_fused<<<NROW / 32, 256, 0, stream>>>(query, Ws, bs, Wa, ba, qpts,
                                                loc, attw);
    // 3. slab-pruned exact KNN (dense LDS scans, wave-per-row locality)
    knn_slab_kernel<<<NROW / 4, 256, 0, stream>>>(loc, spts, cellstart, sbox, idx);
    // 4. gather-blend + per-head value GEMM (134M MAC)
    blend_gemm_kernel<<<dim3(NROW / 128, MH, 2), 256, 0, stream>>>(
        inp, attw, idx, Wv, part);
    // 5. output GEMM, merging K-halves + value bias (134M MAC)
    out_gemm_kernel<<<dim3(NROW / 64, CH / 32), 256, 0, stream>>>(
        part, bv, Wo, bo, out);
}